// Round 10
// baseline (5971.482 us; speedup 1.0000x reference)
//
#include <hip/hip_runtime.h>

#define Bn  64
#define Ln  1024
#define Pn  64
#define Hn  256
#define THn 768
#define ONn 128

typedef __attribute__((ext_vector_type(8))) short short8;
typedef __attribute__((ext_vector_type(4))) float f32x4;
typedef __attribute__((ext_vector_type(4))) int   i32x4;

__device__ __forceinline__ unsigned short f2bf(float f) {
    unsigned u = __float_as_uint(f);
    unsigned r = (u + 0x7FFFu + ((u >> 16) & 1u)) >> 16;
    return (unsigned short)r;
}
__device__ __forceinline__ float bf2f(unsigned short s) {
    return __uint_as_float(((unsigned)s) << 16);
}
__device__ __forceinline__ float sigm(float x) { return 1.0f / (1.0f + __expf(-x)); }
// branch-free tanh via v_exp_f32; exact at saturation (exp->inf => 1, exp->0 => -1)
__device__ __forceinline__ float ftanh(float x) { return 1.0f - 2.0f / (__expf(2.0f * x) + 1.0f); }

__device__ __forceinline__ short8 pack8(const float* __restrict__ p) {
    const float4 f0 = *(const float4*)p;
    const float4 f1 = *(const float4*)(p + 4);
    short8 r;
    r[0] = (short)f2bf(f0.x); r[1] = (short)f2bf(f0.y);
    r[2] = (short)f2bf(f0.z); r[3] = (short)f2bf(f0.w);
    r[4] = (short)f2bf(f1.x); r[5] = (short)f2bf(f1.y);
    r[6] = (short)f2bf(f1.z); r[7] = (short)f2bf(f1.w);
    return r;
}

// ---------------------------------------------------------------------------
// K1: gi_e[b,t,col] = x[b,t,:] @ W_ih_e[col,:] + b_ih_e[col] (+ b_hh_e[col] for r,z)
// stored bf16. Grid 512, block 256 (4 waves). Wave w covers cols [192w,192w+192).
// ---------------------------------------------------------------------------
__global__ __launch_bounds__(256) void k1_gi(const float* __restrict__ x,
        const float* __restrict__ Wih, const float* __restrict__ bih,
        const float* __restrict__ bhh, unsigned short* __restrict__ gi) {
    const int tid = threadIdx.x;
    const int wv = tid >> 6;
    const int lane = tid & 63;
    const int l15 = lane & 15;
    const int grp = lane >> 4;
    const long row0 = (long)blockIdx.x * 128;

    short8 wf[12][2];
#pragma unroll
    for (int tn = 0; tn < 12; ++tn) {
        const int col = 192 * wv + 16 * tn + l15;
#pragma unroll
        for (int tk = 0; tk < 2; ++tk)
            wf[tn][tk] = pack8(Wih + (long)col * Pn + 32 * tk + 8 * grp);
    }
    float biasv[12];
#pragma unroll
    for (int tn = 0; tn < 12; ++tn) {
        const int col = 192 * wv + 16 * tn + l15;
        biasv[tn] = bih[col] + (col < 512 ? bhh[col] : 0.0f); // fold b_hh into r,z gates
    }

    for (int m = 0; m < 8; ++m) {
        const long arow = row0 + 16 * m + l15;
        short8 af[2];
#pragma unroll
        for (int tk = 0; tk < 2; ++tk)
            af[tk] = pack8(x + arow * Pn + 32 * tk + 8 * grp);
#pragma unroll
        for (int tn = 0; tn < 12; ++tn) {
            f32x4 z4 = {0.f, 0.f, 0.f, 0.f};
            f32x4 acc = __builtin_amdgcn_mfma_f32_16x16x32_bf16(af[0], wf[tn][0], z4, 0, 0, 0);
            acc = __builtin_amdgcn_mfma_f32_16x16x32_bf16(af[1], wf[tn][1], acc, 0, 0, 0);
#pragma unroll
            for (int r = 0; r < 4; ++r) {
                const long row = row0 + 16 * m + 4 * grp + r;
                gi[row * THn + 192 * wv + 16 * tn + l15] = f2bf(acc[r] + biasv[tn]);
            }
        }
    }
}

// ---------------------------------------------------------------------------
// K2/K4: persistent GRU recurrence, INT8 matvec, TWO batches per block.
// Block = 1024 thr = 16 waves: waves 0-7 -> batch 2*blk, waves 8-15 -> batch
// 2*blk+1. Each SIMD hosts 2 waves of EACH group. Groups synchronize with
// INDEPENDENT software barriers so the two recurrences drift out of phase:
// one group's gate/publish tail overlaps the other group's MFMA issue (m114).
// R9 POST-MORTEM FIX: the barrier atomics are RELAXED (R9's RELEASE/ACQUIRE
// emitted a full vmcnt(0) drain per step -> dragged the gi prefetch's ~900cy
// HBM latency onto the critical path; 5x regression). Ordering without
// fences: publisher drains its OWN LDS writes (lgkmcnt(0)) BEFORE ds_add;
// consumer's spin exit control-depends on observing the count, LDS is
// uncached, so post-spin ds_reads see published data. R9 passed correctness
// with this exact structure => protocol is verified; only the fences change.
// Per-wave math/quantization identical to R7 => bit-identical outputs.
// ---------------------------------------------------------------------------
template<int DEC>
__global__ __launch_bounds__(1024) void k_rec(
    const float* __restrict__ Whh, const float* __restrict__ bhh,
    const unsigned short* __restrict__ gi_bf,   // encoder: (B,L,768) bf16
    const float* __restrict__ gi_c,             // decoder: (B,768) f32 (biases folded)
    const float* __restrict__ s0,               // dec: last_h (B,256) f32
    unsigned short* __restrict__ h_seq,         // enc out: (B,L,256) bf16
    float* __restrict__ s_seq,                  // dec out: (B,L,256) f32
    float* __restrict__ last_h)                 // enc out: (B,256) f32
{
    const int tid  = threadIdx.x;
    const int w    = tid >> 6;        // 0..15
    const int g2   = w >> 3;          // batch group within block (0/1)
    const int wg   = w & 7;           // wave index within group
    const int b    = blockIdx.x * 2 + g2;
    const int lane = tid & 63;
    const int l15  = lane & 15;
    const int grp  = lane >> 4;
    const int hb   = 32 * wg;         // group-local hidden-slice base
    const int jj   = grp & 1;         // which col-tile this lane owns
    const int unit = hb + 16 * jj + l15;   // this lane's hidden unit

    __shared__ i32x4 hbuf4[2][2][16]; // [group][parity][16x16B] int8 h state
    __shared__ int ctrbuf[32];        // two counters, 64B apart
    char* const hb8 = (char*)hbuf4;   // flat: g2*512 + par*256 + idx
    int* const ctr = &ctrbuf[g2 * 16];

    // ---- quantize W_hh columns to i8 (once; identical in both groups) ----
    i32x4 wf[6][4];
    float swq[6];                     // colmax/(127*127)
#pragma unroll
    for (int tn = 0; tn < 6; ++tn) {
        const int g = tn >> 1, j = tn & 1;
        const int col = 256 * g + hb + 16 * j + l15;
        const float* wp = Whh + (long)col * Hn + 16 * grp;
        float amax = 0.0f;
#pragma unroll
        for (int tk = 0; tk < 4; ++tk) {
            const float* p = wp + 64 * tk;
#pragma unroll
            for (int q = 0; q < 4; ++q) {
                const float4 f = ((const float4*)p)[q];
                amax = fmaxf(amax, fmaxf(fmaxf(fabsf(f.x), fabsf(f.y)),
                                         fmaxf(fabsf(f.z), fabsf(f.w))));
            }
        }
        amax = fmaxf(amax, __shfl_xor(amax, 16));   // reduce across the 4 groups
        amax = fmaxf(amax, __shfl_xor(amax, 32));
        amax = fmaxf(amax, 1e-20f);
        const float inv_sw = 127.0f / amax;
        swq[tn] = amax * (1.0f / (127.0f * 127.0f));
#pragma unroll
        for (int tk = 0; tk < 4; ++tk) {
            const float* p = wp + 64 * tk;
            i32x4 r;
#pragma unroll
            for (int q = 0; q < 4; ++q) {
                const float4 f = ((const float4*)p)[q];
                const int b0 = (int)rintf(f.x * inv_sw) & 255;
                const int b1 = (int)rintf(f.y * inv_sw) & 255;
                const int b2 = (int)rintf(f.z * inv_sw) & 255;
                const int b3 = (int)rintf(f.w * inv_sw) & 255;
                r[q] = b0 | (b1 << 8) | (b2 << 16) | (b3 << 24);
            }
            wf[tn][tk] = r;
        }
    }
    const float swr = jj ? swq[1] : swq[0];
    const float swz = jj ? swq[3] : swq[2];
    const float swn = jj ? swq[5] : swq[4];
    const float bhn = bhh[512 + unit];

    float hprev;
    unsigned short giA[3], giB[3];
    float gic[3];

    const unsigned short* gl = nullptr;   // enc gi prefetch cursor
    unsigned short* hsp = nullptr;        // enc h_seq store cursor
    float* ssp = nullptr;                 // dec s_seq store cursor

    if (tid < 32) ctrbuf[tid] = 0;
    if (!DEC) {
        hprev = 0.0f;
        hb8[tid] = 0;                     // 1024 threads zero both groups/parities
        gl = gi_bf + (long)b * Ln * THn + unit;
#pragma unroll
        for (int g = 0; g < 3; ++g) giA[g] = gl[256 * g];
        hsp = h_seq + (long)b * Ln * Hn + unit;
    } else {
        hprev = s0[b * Hn + unit];
        if (tid < 512) {
            const int gg = tid >> 8, uu = tid & 255;
            hb8[gg * 512 + uu] =
                (char)(int)rintf(s0[(blockIdx.x * 2 + gg) * Hn + uu] * 127.0f);
        }
#pragma unroll
        for (int g = 0; g < 3; ++g) gic[g] = gi_c[(long)b * THn + 256 * g + unit];
        ssp = s_seq + (long)b * Ln * Hn + unit;
    }
    __syncthreads();   // one hardware barrier for init visibility

    auto gbar = [&](int tgt) {
        // drain OWN LDS writes only, then signal; RELAXED spin (no fences,
        // no vmcnt drain — the whole point vs R9)
        asm volatile("s_waitcnt lgkmcnt(0)" ::: "memory");
        if (lane == 0)
            __hip_atomic_fetch_add(ctr, 1, __ATOMIC_RELAXED, __HIP_MEMORY_SCOPE_WORKGROUP);
        while (__hip_atomic_load(ctr, __ATOMIC_RELAXED, __HIP_MEMORY_SCOPE_WORKGROUP) < tgt)
            __builtin_amdgcn_s_sleep(1);
        __builtin_amdgcn_sched_barrier(0);
    };

    auto step = [&](int t, unsigned short (&gU)[3], unsigned short (&gP)[3]) {
        const int par = t & 1;
        const int nxt = par ^ 1;
        // 1. prefetch gi[t+1] (encoder only) — stays in flight (no vmcnt anywhere).
        //    Final step's prefetch reads past gi_e into the allocated h_seq region.
        if (!DEC) {
            gl += THn;
#pragma unroll
            for (int g = 0; g < 3; ++g) gP[g] = gl[256 * g];
        }
        // 2. gh = h @ Whh^T : 24 i8 MFMAs/wave, per-tk ds_read/MFMA interleave
        //    (R5/R7-proven schedule — single block, do not split)
        i32x4 acc[6];
#pragma unroll
        for (int tk = 0; tk < 4; ++tk) {
            const i32x4 af = *(const i32x4*)&hb8[g2 * 512 + par * 256 + 64 * tk + 16 * grp];
            if (tk == 0) {
                const i32x4 zi = {0, 0, 0, 0};
#pragma unroll
                for (int tn = 0; tn < 6; ++tn)
                    acc[tn] = __builtin_amdgcn_mfma_i32_16x16x64_i8(af, wf[tn][0], zi, 0, 0, 0);
            } else {
#pragma unroll
                for (int tn = 0; tn < 6; ++tn)
                    acc[tn] = __builtin_amdgcn_mfma_i32_16x16x64_i8(af, wf[tn][tk], acc[tn], 0, 0, 0);
            }
        }
        // 3. gates — once per unit (lane's jj selects its tile via cndmask)
        const int ar = jj ? acc[1][0] : acc[0][0];
        const int az = jj ? acc[3][0] : acc[2][0];
        const int an = jj ? acc[5][0] : acc[4][0];
        const float gir = DEC ? gic[0] : bf2f(gU[0]);
        const float giz = DEC ? gic[1] : bf2f(gU[1]);
        const float gin = DEC ? gic[2] : bf2f(gU[2]);
        const float r = sigm((float)ar * swr + gir);    // b_hh_r folded upstream
        const float z = sigm((float)az * swz + giz);    // b_hh_z folded upstream
        const float n = ftanh(gin + r * ((float)an * swn + bhn));
        const float hnew = (1.0f - z) * n + z * hprev;
        hprev = hnew;
        // 4. publish h (i8, parity double-buffer) + state-sequence store
        if (grp < 2) {
            hb8[g2 * 512 + nxt * 256 + unit] = (char)(int)rintf(hnew * 127.0f);
            if (!DEC) hsp[0] = f2bf(hnew);
            else      ssp[0] = hnew;
        }
        if (!DEC) hsp += Hn; else ssp += Hn;
        // 5. group-local software barrier (other group runs free)
        gbar(8 * t + 8);
    };

    for (int t = 0; t < Ln; t += 2) {
        step(t, giA, giB);
        step(t + 1, giB, giA);
    }

    if (!DEC) {
        if (grp < 2) last_h[b * Hn + unit] = hprev;
    }
}

// ---------------------------------------------------------------------------
// K3: h_proj[l] = h_seq[b,l,:]·wa_h; alpha = softmax(h_proj); c = sum alpha*h;
// gi_d = c@Wihd^T + biases. h_proj phase: whole-wave dot per row (coalesced
// 512B row reads), 4 rows in flight per wave to hide shfl latency.
// ---------------------------------------------------------------------------
__global__ __launch_bounds__(256) void k3_ctx(const unsigned short* __restrict__ h_seq,
        const float* __restrict__ Wattn, const float* __restrict__ Wihd,
        const float* __restrict__ bihd, const float* __restrict__ bhhd,
        float* __restrict__ gi_d) {
    const int b = blockIdx.x;
    const int tid = threadIdx.x;
    const int wv = tid >> 6, lane = tid & 63;
    __shared__ float alpha[Ln];
    __shared__ float red[8];
    __shared__ float cbuf[Hn];
    __shared__ float wah[Hn];

    wah[tid] = Wattn[Hn + tid];   // wa_h = W_attn[0, H:2H]
    __syncthreads();

    const unsigned short* hb_ = h_seq + (long)b * Ln * Hn;
    const float4 wv4 = ((const float4*)wah)[lane];   // wa_h[4*lane .. 4*lane+3]

    // phase A: raw attention scores -> alpha[]
    for (int it = 0; it < 64; ++it) {
        const int lbase = it * 16 + wv * 4;          // 4 waves x 4 rows = 16 rows/iter
        const uint2 w0 = ((const uint2*)(hb_ + (long)(lbase + 0) * Hn))[lane];
        const uint2 w1 = ((const uint2*)(hb_ + (long)(lbase + 1) * Hn))[lane];
        const uint2 w2 = ((const uint2*)(hb_ + (long)(lbase + 2) * Hn))[lane];
        const uint2 w3 = ((const uint2*)(hb_ + (long)(lbase + 3) * Hn))[lane];
        float p0 = __uint_as_float(w0.x << 16) * wv4.x + __uint_as_float(w0.x & 0xffff0000u) * wv4.y
                 + __uint_as_float(w0.y << 16) * wv4.z + __uint_as_float(w0.y & 0xffff0000u) * wv4.w;
        float p1 = __uint_as_float(w1.x << 16) * wv4.x + __uint_as_float(w1.x & 0xffff0000u) * wv4.y
                 + __uint_as_float(w1.y << 16) * wv4.z + __uint_as_float(w1.y & 0xffff0000u) * wv4.w;
        float p2 = __uint_as_float(w2.x << 16) * wv4.x + __uint_as_float(w2.x & 0xffff0000u) * wv4.y
                 + __uint_as_float(w2.y << 16) * wv4.z + __uint_as_float(w2.y & 0xffff0000u) * wv4.w;
        float p3 = __uint_as_float(w3.x << 16) * wv4.x + __uint_as_float(w3.x & 0xffff0000u) * wv4.y
                 + __uint_as_float(w3.y << 16) * wv4.z + __uint_as_float(w3.y & 0xffff0000u) * wv4.w;
#pragma unroll
        for (int s = 1; s < 64; s <<= 1) {
            p0 += __shfl_xor(p0, s);
            p1 += __shfl_xor(p1, s);
            p2 += __shfl_xor(p2, s);
            p3 += __shfl_xor(p3, s);
        }
        if (lane == 0) {
            alpha[lbase + 0] = p0; alpha[lbase + 1] = p1;
            alpha[lbase + 2] = p2; alpha[lbase + 3] = p3;
        }
    }
    __syncthreads();

    // softmax over alpha[0..Ln)
    const float4 hp4 = ((const float4*)alpha)[tid];
    float m = fmaxf(fmaxf(hp4.x, hp4.y), fmaxf(hp4.z, hp4.w));
#pragma unroll
    for (int s = 1; s < 64; s <<= 1) m = fmaxf(m, __shfl_xor(m, s));
    if (lane == 0) red[wv] = m;
    __syncthreads();
    m = fmaxf(fmaxf(red[0], red[1]), fmaxf(red[2], red[3]));
    const float e0 = __expf(hp4.x - m), e1 = __expf(hp4.y - m);
    const float e2 = __expf(hp4.z - m), e3 = __expf(hp4.w - m);
    float ss = e0 + e1 + e2 + e3;
#pragma unroll
    for (int s = 1; s < 64; s <<= 1) ss += __shfl_xor(ss, s);
    if (lane == 0) red[4 + wv] = ss;
    __syncthreads();
    const float inv = 1.0f / (red[4] + red[5] + red[6] + red[7]);
    ((float4*)alpha)[tid] = make_float4(e0 * inv, e1 * inv, e2 * inv, e3 * inv);
    __syncthreads();

    // context accumulation (column-coalesced)
    float accv = 0.0f;
    const unsigned short* hs = hb_ + tid;
    for (int l = 0; l < Ln; ++l) accv += alpha[l] * bf2f(hs[(long)l * Hn]);
    cbuf[tid] = accv;
    __syncthreads();

    // gi_d = c @ Wihd^T + biases
    for (int c = wv; c < THn; c += 4) {
        const float4 wr = ((const float4*)(Wihd + (long)c * Hn))[lane];
        const float4 cc = ((const float4*)cbuf)[lane];
        float p = wr.x * cc.x + wr.y * cc.y + wr.z * cc.z + wr.w * cc.w;
#pragma unroll
        for (int s = 1; s < 64; s <<= 1) p += __shfl_xor(p, s);
        if (lane == 0)
            gi_d[(long)b * THn + c] = p + bihd[c] + (c < 512 ? bhhd[c] : 0.0f);
    }
}

// ---------------------------------------------------------------------------
// K5: y[l] = sigm(s_seq[b,l,:]·W_dec + b_dec); out[b,o] = y·W_out[o,:] + b_out[o]
// ---------------------------------------------------------------------------
__global__ __launch_bounds__(256) void k5_out(const float* __restrict__ s_seq,
        const float* __restrict__ Wdec, const float* __restrict__ bdec,
        const float* __restrict__ Wout, const float* __restrict__ bout,
        float* __restrict__ out) {
    const int b = blockIdx.x;
    const int tid = threadIdx.x, wv = tid >> 6, lane = tid & 63;
    __shared__ float yl[Ln];
    __shared__ float wd[Hn];
    wd[tid] = Wdec[tid];
    __syncthreads();

    const float* sb = s_seq + (long)b * Ln * Hn;
    const float4 wd4 = ((const float4*)wd)[lane];
    const float bd = bdec[0];

    for (int it = 0; it < 64; ++it) {
        const int lbase = it * 16 + wv * 4;
        const float4 v0 = ((const float4*)(sb + (long)(lbase + 0) * Hn))[lane];
        const float4 v1 = ((const float4*)(sb + (long)(lbase + 1) * Hn))[lane];
        const float4 v2 = ((const float4*)(sb + (long)(lbase + 2) * Hn))[lane];
        const float4 v3 = ((const float4*)(sb + (long)(lbase + 3) * Hn))[lane];
        float p0 = v0.x * wd4.x + v0.y * wd4.y + v0.z * wd4.z + v0.w * wd4.w;
        float p1 = v1.x * wd4.x + v1.y * wd4.y + v1.z * wd4.z + v1.w * wd4.w;
        float p2 = v2.x * wd4.x + v2.y * wd4.y + v2.z * wd4.z + v2.w * wd4.w;
        float p3 = v3.x * wd4.x + v3.y * wd4.y + v3.z * wd4.z + v3.w * wd4.w;
#pragma unroll
        for (int s = 1; s < 64; s <<= 1) {
            p0 += __shfl_xor(p0, s);
            p1 += __shfl_xor(p1, s);
            p2 += __shfl_xor(p2, s);
            p3 += __shfl_xor(p3, s);
        }
        if (lane == 0) {
            yl[lbase + 0] = sigm(p0 + bd); yl[lbase + 1] = sigm(p1 + bd);
            yl[lbase + 2] = sigm(p2 + bd); yl[lbase + 3] = sigm(p3 + bd);
        }
    }
    __syncthreads();

    for (int o = wv; o < ONn; o += 4) {
        const float* wr = Wout + (long)o * Ln;
        float p = 0.0f;
#pragma unroll
        for (int i = 0; i < 16; ++i) p += yl[lane + 64 * i] * wr[lane + 64 * i];
#pragma unroll
        for (int s = 1; s < 64; s <<= 1) p += __shfl_xor(p, s);
        if (lane == 0) out[b * ONn + o] = p + bout[o];
    }
}

// ---------------------------------------------------------------------------
extern "C" void kernel_launch(void* const* d_in, const int* in_sizes, int n_in,
                              void* d_out, int out_size, void* d_ws, size_t ws_size,
                              hipStream_t stream) {
    const float* x      = (const float*)d_in[0];
    const float* Wih_e  = (const float*)d_in[1];
    const float* Whh_e  = (const float*)d_in[2];
    const float* bih_e  = (const float*)d_in[3];
    const float* bhh_e  = (const float*)d_in[4];
    const float* Wih_d  = (const float*)d_in[5];
    const float* Whh_d  = (const float*)d_in[6];
    const float* bih_d  = (const float*)d_in[7];
    const float* bhh_d  = (const float*)d_in[8];
    const float* Wdec   = (const float*)d_in[9];
    const float* bdec   = (const float*)d_in[10];
    const float* Wattn  = (const float*)d_in[11];
    const float* Wout   = (const float*)d_in[13];
    const float* bout   = (const float*)d_in[14];
    float* out = (float*)d_out;

    char* ws = (char*)d_ws;
    unsigned short* gi_e  = (unsigned short*)ws;                    // [0, 100663296) 96 MB
    unsigned short* h_seq = (unsigned short*)(ws + 100663296);      // 32 MB
    float* last_h = (float*)(ws + 134217728);                       // 64 KB
    float* gi_d   = (float*)(ws + 134283264);                       // 192 KB
    float* s_seq  = (float*)ws;                                     // reuse gi_e (dead after enc), 64 MB

    k1_gi<<<512, 256, 0, stream>>>(x, Wih_e, bih_e, bhh_e, gi_e);
    k_rec<0><<<Bn / 2, 1024, 0, stream>>>(Whh_e, bhh_e, gi_e, nullptr, nullptr,
                                          h_seq, nullptr, last_h);
    k3_ctx<<<Bn, 256, 0, stream>>>(h_seq, Wattn, Wih_d, bih_d, bhh_d, gi_d);
    k_rec<1><<<Bn / 2, 1024, 0, stream>>>(Whh_d, bhh_d, nullptr, gi_d, last_h,
                                          nullptr, s_seq, nullptr);
    k5_out<<<Bn, 256, 0, stream>>>(s_seq, Wdec, bdec, Wout, bout, out);
}

// Round 11
// 1674.027 us; speedup vs baseline: 3.5671x; 3.5671x over previous
//
#include <hip/hip_runtime.h>

#define Bn  64
#define Ln  1024
#define Pn  64
#define Hn  256
#define THn 768
#define ONn 128

typedef __attribute__((ext_vector_type(8))) short short8;
typedef __attribute__((ext_vector_type(4))) float f32x4;
typedef __attribute__((ext_vector_type(4))) int   i32x4;

__device__ __forceinline__ unsigned short f2bf(float f) {
    unsigned u = __float_as_uint(f);
    unsigned r = (u + 0x7FFFu + ((u >> 16) & 1u)) >> 16;
    return (unsigned short)r;
}
__device__ __forceinline__ float bf2f(unsigned short s) {
    return __uint_as_float(((unsigned)s) << 16);
}
__device__ __forceinline__ float sigm(float x) { return 1.0f / (1.0f + __expf(-x)); }
// branch-free tanh via v_exp_f32; exact at saturation (exp->inf => 1, exp->0 => -1)
__device__ __forceinline__ float ftanh(float x) { return 1.0f - 2.0f / (__expf(2.0f * x) + 1.0f); }

__device__ __forceinline__ short8 pack8(const float* __restrict__ p) {
    const float4 f0 = *(const float4*)p;
    const float4 f1 = *(const float4*)(p + 4);
    short8 r;
    r[0] = (short)f2bf(f0.x); r[1] = (short)f2bf(f0.y);
    r[2] = (short)f2bf(f0.z); r[3] = (short)f2bf(f0.w);
    r[4] = (short)f2bf(f1.x); r[5] = (short)f2bf(f1.y);
    r[6] = (short)f2bf(f1.z); r[7] = (short)f2bf(f1.w);
    return r;
}

// ---------------------------------------------------------------------------
// K1: gi_e[b,t,col] = x[b,t,:] @ W_ih_e[col,:] + b_ih_e[col] (+ b_hh_e[col] for r,z)
// stored bf16. Grid 512, block 256 (4 waves). Wave w covers cols [192w,192w+192).
// ---------------------------------------------------------------------------
__global__ __launch_bounds__(256) void k1_gi(const float* __restrict__ x,
        const float* __restrict__ Wih, const float* __restrict__ bih,
        const float* __restrict__ bhh, unsigned short* __restrict__ gi) {
    const int tid = threadIdx.x;
    const int wv = tid >> 6;
    const int lane = tid & 63;
    const int l15 = lane & 15;
    const int grp = lane >> 4;
    const long row0 = (long)blockIdx.x * 128;

    short8 wf[12][2];
#pragma unroll
    for (int tn = 0; tn < 12; ++tn) {
        const int col = 192 * wv + 16 * tn + l15;
#pragma unroll
        for (int tk = 0; tk < 2; ++tk)
            wf[tn][tk] = pack8(Wih + (long)col * Pn + 32 * tk + 8 * grp);
    }
    float biasv[12];
#pragma unroll
    for (int tn = 0; tn < 12; ++tn) {
        const int col = 192 * wv + 16 * tn + l15;
        biasv[tn] = bih[col] + (col < 512 ? bhh[col] : 0.0f); // fold b_hh into r,z gates
    }

    for (int m = 0; m < 8; ++m) {
        const long arow = row0 + 16 * m + l15;
        short8 af[2];
#pragma unroll
        for (int tk = 0; tk < 2; ++tk)
            af[tk] = pack8(x + arow * Pn + 32 * tk + 8 * grp);
#pragma unroll
        for (int tn = 0; tn < 12; ++tn) {
            f32x4 z4 = {0.f, 0.f, 0.f, 0.f};
            f32x4 acc = __builtin_amdgcn_mfma_f32_16x16x32_bf16(af[0], wf[tn][0], z4, 0, 0, 0);
            acc = __builtin_amdgcn_mfma_f32_16x16x32_bf16(af[1], wf[tn][1], acc, 0, 0, 0);
#pragma unroll
            for (int r = 0; r < 4; ++r) {
                const long row = row0 + 16 * m + 4 * grp + r;
                gi[row * THn + 192 * wv + 16 * tn + l15] = f2bf(acc[r] + biasv[tn]);
            }
        }
    }
}

// ---------------------------------------------------------------------------
// K2/K4: persistent GRU recurrence, INT8 matvec (mfma_i32_16x16x64_i8).
// One WG (8 waves, 512 thr) per batch; wave w owns units [32w,32w+32).
// PROVEN R7 KERNEL (best verified: 676 us/dispatch, e2e 1664 us). Permanent
// revert after the dual-batch/software-barrier branch failed 3x (R8 infra,
// R9 fence-drain, R10 register-file contradiction: 16 waves x 96 weight VGPRs
// cannot fit -> scratch spill).
// Structure: prefetch -> per-tk ds_read/MFMA interleave (single block; R3/R6
// proved splitting regresses) -> one-unit-per-lane gates (R7's +36% win) ->
// publish -> lgkmcnt-only barrier (gi prefetch stays in flight).
// Quantization: per-column W scales (colmax/127), h x127 symmetric (|h|<1 by
// GRU convexity), exact i32 accumulate, hprev stays f32.
// ---------------------------------------------------------------------------
template<int DEC>
__global__ __launch_bounds__(512, 2) void k_rec(
    const float* __restrict__ Whh, const float* __restrict__ bhh,
    const unsigned short* __restrict__ gi_bf,   // encoder: (B,L,768) bf16
    const float* __restrict__ gi_c,             // decoder: (B,768) f32 (biases folded)
    const float* __restrict__ s0,               // dec: last_h (B,256) f32
    unsigned short* __restrict__ h_seq,         // enc out: (B,L,256) bf16
    float* __restrict__ s_seq,                  // dec out: (B,L,256) f32
    float* __restrict__ last_h)                 // enc out: (B,256) f32
{
    const int b = blockIdx.x;
    const int tid = threadIdx.x;
    const int wv = tid >> 6;          // 0..7
    const int lane = tid & 63;
    const int l15 = lane & 15;
    const int grp = lane >> 4;
    const int hb = 32 * wv;           // this wave's hidden-slice base
    const int jj = grp & 1;           // which col-tile this lane owns
    const int unit = hb + 16 * jj + l15;   // this lane's hidden unit

    __shared__ i32x4 hbuf4[2][16];    // int8 h state, 256 B per buffer, 16B aligned
    char* const hb8 = (char*)hbuf4;   // flat view: [par*256 + idx]

    // ---- quantize W_hh columns to i8 (once). tn = g*2+j, col per lane ----
    i32x4 wf[6][4];
    float swq[6];                     // sw[col]/127 = colmax/(127*127)
#pragma unroll
    for (int tn = 0; tn < 6; ++tn) {
        const int g = tn >> 1, j = tn & 1;
        const int col = 256 * g + hb + 16 * j + l15;
        const float* wp = Whh + (long)col * Hn + 16 * grp;
        float amax = 0.0f;
#pragma unroll
        for (int tk = 0; tk < 4; ++tk) {
            const float* p = wp + 64 * tk;
#pragma unroll
            for (int q = 0; q < 4; ++q) {
                const float4 f = ((const float4*)p)[q];
                amax = fmaxf(amax, fmaxf(fmaxf(fabsf(f.x), fabsf(f.y)),
                                         fmaxf(fabsf(f.z), fabsf(f.w))));
            }
        }
        amax = fmaxf(amax, __shfl_xor(amax, 16));   // reduce across the 4 groups
        amax = fmaxf(amax, __shfl_xor(amax, 32));
        amax = fmaxf(amax, 1e-20f);
        const float inv_sw = 127.0f / amax;
        swq[tn] = amax * (1.0f / (127.0f * 127.0f));
#pragma unroll
        for (int tk = 0; tk < 4; ++tk) {
            const float* p = wp + 64 * tk;
            i32x4 r;
#pragma unroll
            for (int q = 0; q < 4; ++q) {
                const float4 f = ((const float4*)p)[q];
                const int b0 = (int)rintf(f.x * inv_sw) & 255;
                const int b1 = (int)rintf(f.y * inv_sw) & 255;
                const int b2 = (int)rintf(f.z * inv_sw) & 255;
                const int b3 = (int)rintf(f.w * inv_sw) & 255;
                r[q] = b0 | (b1 << 8) | (b2 << 16) | (b3 << 24);
            }
            wf[tn][tk] = r;
        }
    }
    // per-lane selected scales / bias for the lane's own unit (static indices)
    const float swr = jj ? swq[1] : swq[0];
    const float swz = jj ? swq[3] : swq[2];
    const float swn = jj ? swq[5] : swq[4];
    const float bhn = bhh[512 + unit];

    float hprev;
    unsigned short giA[3], giB[3];
    float gic[3];

    const unsigned short* gl = nullptr;   // enc gi prefetch cursor (per-lane unit)
    unsigned short* hsp = nullptr;        // enc h_seq store cursor
    float* ssp = nullptr;                 // dec s_seq store cursor

    if (!DEC) {
        hprev = 0.0f;
        if (tid < 128) ((int*)hbuf4)[tid] = 0;   // zero both parity buffers
        gl = gi_bf + (long)b * Ln * THn + unit;
#pragma unroll
        for (int g = 0; g < 3; ++g) giA[g] = gl[256 * g];
        hsp = h_seq + (long)b * Ln * Hn + unit;
    } else {
        hprev = s0[b * Hn + unit];
        if (tid < 256) hb8[tid] = (char)(int)rintf(s0[b * Hn + tid] * 127.0f);
        const float* gd = gi_c + (long)b * THn;
#pragma unroll
        for (int g = 0; g < 3; ++g) gic[g] = gd[256 * g + unit];
        ssp = s_seq + (long)b * Ln * Hn + unit;
    }
    __syncthreads();

    auto step = [&](int t, unsigned short (&gU)[3], unsigned short (&gP)[3]) {
        const int par = t & 1;
        const int nxt = par ^ 1;
        // 1. prefetch gi[t+1] (encoder only) — stays in flight across the barrier.
        //    Final step's prefetch reads past gi_e into the allocated h_seq region.
        if (!DEC) {
            gl += THn;
#pragma unroll
            for (int g = 0; g < 3; ++g) gP[g] = gl[256 * g];
        }
        // 2. gh = h @ Whh^T : 24 i8 MFMAs/wave, per-tk ds_read/MFMA interleave
        //    (R5-proven schedule — single block, do not split)
        i32x4 acc[6];
#pragma unroll
        for (int tk = 0; tk < 4; ++tk) {
            const i32x4 af = *(const i32x4*)&hb8[par * 256 + 64 * tk + 16 * grp];
            if (tk == 0) {
                const i32x4 zi = {0, 0, 0, 0};
#pragma unroll
                for (int tn = 0; tn < 6; ++tn)
                    acc[tn] = __builtin_amdgcn_mfma_i32_16x16x64_i8(af, wf[tn][0], zi, 0, 0, 0);
            } else {
#pragma unroll
                for (int tn = 0; tn < 6; ++tn)
                    acc[tn] = __builtin_amdgcn_mfma_i32_16x16x64_i8(af, wf[tn][tk], acc[tn], 0, 0, 0);
            }
        }
        // 3. gates — ONCE per unit (lane's jj selects its tile via cndmask)
        const int ar = jj ? acc[1][0] : acc[0][0];
        const int az = jj ? acc[3][0] : acc[2][0];
        const int an = jj ? acc[5][0] : acc[4][0];
        const float gir = DEC ? gic[0] : bf2f(gU[0]);
        const float giz = DEC ? gic[1] : bf2f(gU[1]);
        const float gin = DEC ? gic[2] : bf2f(gU[2]);
        const float r = sigm((float)ar * swr + gir);    // b_hh_r folded upstream
        const float z = sigm((float)az * swz + giz);    // b_hh_z folded upstream
        const float n = ftanh(gin + r * ((float)an * swn + bhn));
        const float hnew = (1.0f - z) * n + z * hprev;
        hprev = hnew;
        // 4. publish h (i8, double-buffered) + state-sequence store (grp 0,1
        //    cover all 32 units of this wave; grps 2,3 are duplicates)
        if (grp < 2) {
            hb8[nxt * 256 + unit] = (char)(int)rintf(hnew * 127.0f);
            if (!DEC) hsp[0] = f2bf(hnew);
            else      ssp[0] = hnew;
        }
        if (!DEC) hsp += Hn; else ssp += Hn;
        // 5. barrier WITHOUT vmcnt drain (keep prefetch/stores in flight)
        asm volatile("s_waitcnt lgkmcnt(0)\n\ts_barrier" ::: "memory");
    };

    for (int t = 0; t < Ln; t += 2) {
        step(t, giA, giB);
        step(t + 1, giB, giA);
    }

    if (!DEC) {
        if (grp < 2) last_h[b * Hn + unit] = hprev;
    }
}

// ---------------------------------------------------------------------------
// K3: h_proj[l] = h_seq[b,l,:]·wa_h; alpha = softmax(h_proj); c = sum alpha*h;
// gi_d = c@Wihd^T + biases. h_proj phase: whole-wave dot per row (coalesced
// 512B row reads), 4 rows in flight per wave to hide shfl latency.
// ---------------------------------------------------------------------------
__global__ __launch_bounds__(256) void k3_ctx(const unsigned short* __restrict__ h_seq,
        const float* __restrict__ Wattn, const float* __restrict__ Wihd,
        const float* __restrict__ bihd, const float* __restrict__ bhhd,
        float* __restrict__ gi_d) {
    const int b = blockIdx.x;
    const int tid = threadIdx.x;
    const int wv = tid >> 6, lane = tid & 63;
    __shared__ float alpha[Ln];
    __shared__ float red[8];
    __shared__ float cbuf[Hn];
    __shared__ float wah[Hn];

    wah[tid] = Wattn[Hn + tid];   // wa_h = W_attn[0, H:2H]
    __syncthreads();

    const unsigned short* hb_ = h_seq + (long)b * Ln * Hn;
    const float4 wv4 = ((const float4*)wah)[lane];   // wa_h[4*lane .. 4*lane+3]

    // phase A: raw attention scores -> alpha[]
    for (int it = 0; it < 64; ++it) {
        const int lbase = it * 16 + wv * 4;          // 4 waves x 4 rows = 16 rows/iter
        const uint2 w0 = ((const uint2*)(hb_ + (long)(lbase + 0) * Hn))[lane];
        const uint2 w1 = ((const uint2*)(hb_ + (long)(lbase + 1) * Hn))[lane];
        const uint2 w2 = ((const uint2*)(hb_ + (long)(lbase + 2) * Hn))[lane];
        const uint2 w3 = ((const uint2*)(hb_ + (long)(lbase + 3) * Hn))[lane];
        float p0 = __uint_as_float(w0.x << 16) * wv4.x + __uint_as_float(w0.x & 0xffff0000u) * wv4.y
                 + __uint_as_float(w0.y << 16) * wv4.z + __uint_as_float(w0.y & 0xffff0000u) * wv4.w;
        float p1 = __uint_as_float(w1.x << 16) * wv4.x + __uint_as_float(w1.x & 0xffff0000u) * wv4.y
                 + __uint_as_float(w1.y << 16) * wv4.z + __uint_as_float(w1.y & 0xffff0000u) * wv4.w;
        float p2 = __uint_as_float(w2.x << 16) * wv4.x + __uint_as_float(w2.x & 0xffff0000u) * wv4.y
                 + __uint_as_float(w2.y << 16) * wv4.z + __uint_as_float(w2.y & 0xffff0000u) * wv4.w;
        float p3 = __uint_as_float(w3.x << 16) * wv4.x + __uint_as_float(w3.x & 0xffff0000u) * wv4.y
                 + __uint_as_float(w3.y << 16) * wv4.z + __uint_as_float(w3.y & 0xffff0000u) * wv4.w;
#pragma unroll
        for (int s = 1; s < 64; s <<= 1) {
            p0 += __shfl_xor(p0, s);
            p1 += __shfl_xor(p1, s);
            p2 += __shfl_xor(p2, s);
            p3 += __shfl_xor(p3, s);
        }
        if (lane == 0) {
            alpha[lbase + 0] = p0; alpha[lbase + 1] = p1;
            alpha[lbase + 2] = p2; alpha[lbase + 3] = p3;
        }
    }
    __syncthreads();

    // softmax over alpha[0..Ln)
    const float4 hp4 = ((const float4*)alpha)[tid];
    float m = fmaxf(fmaxf(hp4.x, hp4.y), fmaxf(hp4.z, hp4.w));
#pragma unroll
    for (int s = 1; s < 64; s <<= 1) m = fmaxf(m, __shfl_xor(m, s));
    if (lane == 0) red[wv] = m;
    __syncthreads();
    m = fmaxf(fmaxf(red[0], red[1]), fmaxf(red[2], red[3]));
    const float e0 = __expf(hp4.x - m), e1 = __expf(hp4.y - m);
    const float e2 = __expf(hp4.z - m), e3 = __expf(hp4.w - m);
    float ss = e0 + e1 + e2 + e3;
#pragma unroll
    for (int s = 1; s < 64; s <<= 1) ss += __shfl_xor(ss, s);
    if (lane == 0) red[4 + wv] = ss;
    __syncthreads();
    const float inv = 1.0f / (red[4] + red[5] + red[6] + red[7]);
    ((float4*)alpha)[tid] = make_float4(e0 * inv, e1 * inv, e2 * inv, e3 * inv);
    __syncthreads();

    // context accumulation (column-coalesced)
    float accv = 0.0f;
    const unsigned short* hs = hb_ + tid;
    for (int l = 0; l < Ln; ++l) accv += alpha[l] * bf2f(hs[(long)l * Hn]);
    cbuf[tid] = accv;
    __syncthreads();

    // gi_d = c @ Wihd^T + biases
    for (int c = wv; c < THn; c += 4) {
        const float4 wr = ((const float4*)(Wihd + (long)c * Hn))[lane];
        const float4 cc = ((const float4*)cbuf)[lane];
        float p = wr.x * cc.x + wr.y * cc.y + wr.z * cc.z + wr.w * cc.w;
#pragma unroll
        for (int s = 1; s < 64; s <<= 1) p += __shfl_xor(p, s);
        if (lane == 0)
            gi_d[(long)b * THn + c] = p + bihd[c] + (c < 512 ? bhhd[c] : 0.0f);
    }
}

// ---------------------------------------------------------------------------
// K5: y[l] = sigm(s_seq[b,l,:]·W_dec + b_dec); out[b,o] = y·W_out[o,:] + b_out[o]
// ---------------------------------------------------------------------------
__global__ __launch_bounds__(256) void k5_out(const float* __restrict__ s_seq,
        const float* __restrict__ Wdec, const float* __restrict__ bdec,
        const float* __restrict__ Wout, const float* __restrict__ bout,
        float* __restrict__ out) {
    const int b = blockIdx.x;
    const int tid = threadIdx.x, wv = tid >> 6, lane = tid & 63;
    __shared__ float yl[Ln];
    __shared__ float wd[Hn];
    wd[tid] = Wdec[tid];
    __syncthreads();

    const float* sb = s_seq + (long)b * Ln * Hn;
    const float4 wd4 = ((const float4*)wd)[lane];
    const float bd = bdec[0];

    for (int it = 0; it < 64; ++it) {
        const int lbase = it * 16 + wv * 4;
        const float4 v0 = ((const float4*)(sb + (long)(lbase + 0) * Hn))[lane];
        const float4 v1 = ((const float4*)(sb + (long)(lbase + 1) * Hn))[lane];
        const float4 v2 = ((const float4*)(sb + (long)(lbase + 2) * Hn))[lane];
        const float4 v3 = ((const float4*)(sb + (long)(lbase + 3) * Hn))[lane];
        float p0 = v0.x * wd4.x + v0.y * wd4.y + v0.z * wd4.z + v0.w * wd4.w;
        float p1 = v1.x * wd4.x + v1.y * wd4.y + v1.z * wd4.z + v1.w * wd4.w;
        float p2 = v2.x * wd4.x + v2.y * wd4.y + v2.z * wd4.z + v2.w * wd4.w;
        float p3 = v3.x * wd4.x + v3.y * wd4.y + v3.z * wd4.z + v3.w * wd4.w;
#pragma unroll
        for (int s = 1; s < 64; s <<= 1) {
            p0 += __shfl_xor(p0, s);
            p1 += __shfl_xor(p1, s);
            p2 += __shfl_xor(p2, s);
            p3 += __shfl_xor(p3, s);
        }
        if (lane == 0) {
            yl[lbase + 0] = sigm(p0 + bd); yl[lbase + 1] = sigm(p1 + bd);
            yl[lbase + 2] = sigm(p2 + bd); yl[lbase + 3] = sigm(p3 + bd);
        }
    }
    __syncthreads();

    for (int o = wv; o < ONn; o += 4) {
        const float* wr = Wout + (long)o * Ln;
        float p = 0.0f;
#pragma unroll
        for (int i = 0; i < 16; ++i) p += yl[lane + 64 * i] * wr[lane + 64 * i];
#pragma unroll
        for (int s = 1; s < 64; s <<= 1) p += __shfl_xor(p, s);
        if (lane == 0) out[b * ONn + o] = p + bout[o];
    }
}

// ---------------------------------------------------------------------------
extern "C" void kernel_launch(void* const* d_in, const int* in_sizes, int n_in,
                              void* d_out, int out_size, void* d_ws, size_t ws_size,
                              hipStream_t stream) {
    const float* x      = (const float*)d_in[0];
    const float* Wih_e  = (const float*)d_in[1];
    const float* Whh_e  = (const float*)d_in[2];
    const float* bih_e  = (const float*)d_in[3];
    const float* bhh_e  = (const float*)d_in[4];
    const float* Wih_d  = (const float*)d_in[5];
    const float* Whh_d  = (const float*)d_in[6];
    const float* bih_d  = (const float*)d_in[7];
    const float* bhh_d  = (const float*)d_in[8];
    const float* Wdec   = (const float*)d_in[9];
    const float* bdec   = (const float*)d_in[10];
    const float* Wattn  = (const float*)d_in[11];
    const float* Wout   = (const float*)d_in[13];
    const float* bout   = (const float*)d_in[14];
    float* out = (float*)d_out;

    char* ws = (char*)d_ws;
    unsigned short* gi_e  = (unsigned short*)ws;                    // [0, 100663296) 96 MB
    unsigned short* h_seq = (unsigned short*)(ws + 100663296);      // 32 MB
    float* last_h = (float*)(ws + 134217728);                       // 64 KB
    float* gi_d   = (float*)(ws + 134283264);                       // 192 KB
    float* s_seq  = (float*)ws;                                     // reuse gi_e (dead after enc), 64 MB

    k1_gi<<<512, 256, 0, stream>>>(x, Wih_e, bih_e, bhh_e, gi_e);
    k_rec<0><<<Bn, 512, 0, stream>>>(Whh_e, bhh_e, gi_e, nullptr, nullptr,
                                     h_seq, nullptr, last_h);
    k3_ctx<<<Bn, 256, 0, stream>>>(h_seq, Wattn, Wih_d, bih_d, bhh_d, gi_d);
    k_rec<1><<<Bn, 512, 0, stream>>>(Whh_d, bhh_d, nullptr, gi_d, last_h,
                                     nullptr, s_seq, nullptr);
    k5_out<<<Bn, 256, 0, stream>>>(s_seq, Wdec, bdec, Wout, bout, out);
}

// Round 12
// 1628.177 us; speedup vs baseline: 3.6676x; 1.0282x over previous
//
#include <hip/hip_runtime.h>

#define Bn  64
#define Ln  1024
#define Pn  64
#define Hn  256
#define THn 768
#define ONn 128

typedef __attribute__((ext_vector_type(8))) short short8;
typedef __attribute__((ext_vector_type(4))) float f32x4;
typedef __attribute__((ext_vector_type(4))) int   i32x4;

__device__ __forceinline__ unsigned short f2bf(float f) {
    unsigned u = __float_as_uint(f);
    unsigned r = (u + 0x7FFFu + ((u >> 16) & 1u)) >> 16;
    return (unsigned short)r;
}
__device__ __forceinline__ float bf2f(unsigned short s) {
    return __uint_as_float(((unsigned)s) << 16);
}
__device__ __forceinline__ float sigm(float x) { return 1.0f / (1.0f + __expf(-x)); }
// branch-free tanh via v_exp_f32; exact at saturation (exp->inf => 1, exp->0 => -1)
__device__ __forceinline__ float ftanh(float x) { return 1.0f - 2.0f / (__expf(2.0f * x) + 1.0f); }

__device__ __forceinline__ short8 pack8(const float* __restrict__ p) {
    const float4 f0 = *(const float4*)p;
    const float4 f1 = *(const float4*)(p + 4);
    short8 r;
    r[0] = (short)f2bf(f0.x); r[1] = (short)f2bf(f0.y);
    r[2] = (short)f2bf(f0.z); r[3] = (short)f2bf(f0.w);
    r[4] = (short)f2bf(f1.x); r[5] = (short)f2bf(f1.y);
    r[6] = (short)f2bf(f1.z); r[7] = (short)f2bf(f1.w);
    return r;
}

// ---------------------------------------------------------------------------
// K1: gi_e[b,t,col] = x[b,t,:] @ W_ih_e[col,:] + b_ih_e[col] (+ b_hh_e[col] for r,z)
// stored bf16. Grid 512, block 256 (4 waves). Wave w covers cols [192w,192w+192).
// ---------------------------------------------------------------------------
__global__ __launch_bounds__(256) void k1_gi(const float* __restrict__ x,
        const float* __restrict__ Wih, const float* __restrict__ bih,
        const float* __restrict__ bhh, unsigned short* __restrict__ gi) {
    const int tid = threadIdx.x;
    const int wv = tid >> 6;
    const int lane = tid & 63;
    const int l15 = lane & 15;
    const int grp = lane >> 4;
    const long row0 = (long)blockIdx.x * 128;

    short8 wf[12][2];
#pragma unroll
    for (int tn = 0; tn < 12; ++tn) {
        const int col = 192 * wv + 16 * tn + l15;
#pragma unroll
        for (int tk = 0; tk < 2; ++tk)
            wf[tn][tk] = pack8(Wih + (long)col * Pn + 32 * tk + 8 * grp);
    }
    float biasv[12];
#pragma unroll
    for (int tn = 0; tn < 12; ++tn) {
        const int col = 192 * wv + 16 * tn + l15;
        biasv[tn] = bih[col] + (col < 512 ? bhh[col] : 0.0f); // fold b_hh into r,z gates
    }

    for (int m = 0; m < 8; ++m) {
        const long arow = row0 + 16 * m + l15;
        short8 af[2];
#pragma unroll
        for (int tk = 0; tk < 2; ++tk)
            af[tk] = pack8(x + arow * Pn + 32 * tk + 8 * grp);
#pragma unroll
        for (int tn = 0; tn < 12; ++tn) {
            f32x4 z4 = {0.f, 0.f, 0.f, 0.f};
            f32x4 acc = __builtin_amdgcn_mfma_f32_16x16x32_bf16(af[0], wf[tn][0], z4, 0, 0, 0);
            acc = __builtin_amdgcn_mfma_f32_16x16x32_bf16(af[1], wf[tn][1], acc, 0, 0, 0);
#pragma unroll
            for (int r = 0; r < 4; ++r) {
                const long row = row0 + 16 * m + 4 * grp + r;
                gi[row * THn + 192 * wv + 16 * tn + l15] = f2bf(acc[r] + biasv[tn]);
            }
        }
    }
}

// ---------------------------------------------------------------------------
// K2/K4: persistent GRU recurrence, INT8 matvec (mfma_i32_16x16x64_i8).
// One WG (8 waves, 512 thr) per batch; wave w owns units [32w,32w+32).
// FROZEN R7 KERNEL (best verified: 676 us/dispatch). Structural floor:
// step = 980cy i8-MFMA issue/SIMD (48 x 20.4cy, irreducible: 16x16x64 is the
// best matvec shape; batch-packing M doesn't cut per-block MFMAs; column-
// splitting requires per-step cross-CU sync which loses) + ~600cy serial tail
// (refuted hiding attempts: R3/R6 scheduling, R4 TLP, R2 cross-CU, R8-R10
// intra-CU async barriers).
// Quantization: per-column W scales (colmax/127), h x127 symmetric (|h|<1 by
// GRU convexity), exact i32 accumulate, hprev stays f32.
// ---------------------------------------------------------------------------
template<int DEC>
__global__ __launch_bounds__(512, 2) void k_rec(
    const float* __restrict__ Whh, const float* __restrict__ bhh,
    const unsigned short* __restrict__ gi_bf,   // encoder: (B,L,768) bf16
    const float* __restrict__ gi_c,             // decoder: (B,768) f32 (biases folded)
    const float* __restrict__ s0,               // dec: last_h (B,256) f32
    unsigned short* __restrict__ h_seq,         // enc out: (B,L,256) bf16
    float* __restrict__ s_seq,                  // dec out: (B,L,256) f32
    float* __restrict__ last_h)                 // enc out: (B,256) f32
{
    const int b = blockIdx.x;
    const int tid = threadIdx.x;
    const int wv = tid >> 6;          // 0..7
    const int lane = tid & 63;
    const int l15 = lane & 15;
    const int grp = lane >> 4;
    const int hb = 32 * wv;           // this wave's hidden-slice base
    const int jj = grp & 1;           // which col-tile this lane owns
    const int unit = hb + 16 * jj + l15;   // this lane's hidden unit

    __shared__ i32x4 hbuf4[2][16];    // int8 h state, 256 B per buffer, 16B aligned
    char* const hb8 = (char*)hbuf4;   // flat view: [par*256 + idx]

    // ---- quantize W_hh columns to i8 (once). tn = g*2+j, col per lane ----
    i32x4 wf[6][4];
    float swq[6];                     // sw[col]/127 = colmax/(127*127)
#pragma unroll
    for (int tn = 0; tn < 6; ++tn) {
        const int g = tn >> 1, j = tn & 1;
        const int col = 256 * g + hb + 16 * j + l15;
        const float* wp = Whh + (long)col * Hn + 16 * grp;
        float amax = 0.0f;
#pragma unroll
        for (int tk = 0; tk < 4; ++tk) {
            const float* p = wp + 64 * tk;
#pragma unroll
            for (int q = 0; q < 4; ++q) {
                const float4 f = ((const float4*)p)[q];
                amax = fmaxf(amax, fmaxf(fmaxf(fabsf(f.x), fabsf(f.y)),
                                         fmaxf(fabsf(f.z), fabsf(f.w))));
            }
        }
        amax = fmaxf(amax, __shfl_xor(amax, 16));   // reduce across the 4 groups
        amax = fmaxf(amax, __shfl_xor(amax, 32));
        amax = fmaxf(amax, 1e-20f);
        const float inv_sw = 127.0f / amax;
        swq[tn] = amax * (1.0f / (127.0f * 127.0f));
#pragma unroll
        for (int tk = 0; tk < 4; ++tk) {
            const float* p = wp + 64 * tk;
            i32x4 r;
#pragma unroll
            for (int q = 0; q < 4; ++q) {
                const float4 f = ((const float4*)p)[q];
                const int b0 = (int)rintf(f.x * inv_sw) & 255;
                const int b1 = (int)rintf(f.y * inv_sw) & 255;
                const int b2 = (int)rintf(f.z * inv_sw) & 255;
                const int b3 = (int)rintf(f.w * inv_sw) & 255;
                r[q] = b0 | (b1 << 8) | (b2 << 16) | (b3 << 24);
            }
            wf[tn][tk] = r;
        }
    }
    // per-lane selected scales / bias for the lane's own unit (static indices)
    const float swr = jj ? swq[1] : swq[0];
    const float swz = jj ? swq[3] : swq[2];
    const float swn = jj ? swq[5] : swq[4];
    const float bhn = bhh[512 + unit];

    float hprev;
    unsigned short giA[3], giB[3];
    float gic[3];

    const unsigned short* gl = nullptr;   // enc gi prefetch cursor (per-lane unit)
    unsigned short* hsp = nullptr;        // enc h_seq store cursor
    float* ssp = nullptr;                 // dec s_seq store cursor

    if (!DEC) {
        hprev = 0.0f;
        if (tid < 128) ((int*)hbuf4)[tid] = 0;   // zero both parity buffers
        gl = gi_bf + (long)b * Ln * THn + unit;
#pragma unroll
        for (int g = 0; g < 3; ++g) giA[g] = gl[256 * g];
        hsp = h_seq + (long)b * Ln * Hn + unit;
    } else {
        hprev = s0[b * Hn + unit];
        if (tid < 256) hb8[tid] = (char)(int)rintf(s0[b * Hn + tid] * 127.0f);
        const float* gd = gi_c + (long)b * THn;
#pragma unroll
        for (int g = 0; g < 3; ++g) gic[g] = gd[256 * g + unit];
        ssp = s_seq + (long)b * Ln * Hn + unit;
    }
    __syncthreads();

    auto step = [&](int t, unsigned short (&gU)[3], unsigned short (&gP)[3]) {
        const int par = t & 1;
        const int nxt = par ^ 1;
        // 1. prefetch gi[t+1] (encoder only) — stays in flight across the barrier.
        //    Final step's prefetch reads past gi_e into the allocated h_seq region.
        if (!DEC) {
            gl += THn;
#pragma unroll
            for (int g = 0; g < 3; ++g) gP[g] = gl[256 * g];
        }
        // 2. gh = h @ Whh^T : 24 i8 MFMAs/wave, per-tk ds_read/MFMA interleave
        //    (R5-proven schedule — single block, do not split)
        i32x4 acc[6];
#pragma unroll
        for (int tk = 0; tk < 4; ++tk) {
            const i32x4 af = *(const i32x4*)&hb8[par * 256 + 64 * tk + 16 * grp];
            if (tk == 0) {
                const i32x4 zi = {0, 0, 0, 0};
#pragma unroll
                for (int tn = 0; tn < 6; ++tn)
                    acc[tn] = __builtin_amdgcn_mfma_i32_16x16x64_i8(af, wf[tn][0], zi, 0, 0, 0);
            } else {
#pragma unroll
                for (int tn = 0; tn < 6; ++tn)
                    acc[tn] = __builtin_amdgcn_mfma_i32_16x16x64_i8(af, wf[tn][tk], acc[tn], 0, 0, 0);
            }
        }
        // 3. gates — ONCE per unit (lane's jj selects its tile via cndmask)
        const int ar = jj ? acc[1][0] : acc[0][0];
        const int az = jj ? acc[3][0] : acc[2][0];
        const int an = jj ? acc[5][0] : acc[4][0];
        const float gir = DEC ? gic[0] : bf2f(gU[0]);
        const float giz = DEC ? gic[1] : bf2f(gU[1]);
        const float gin = DEC ? gic[2] : bf2f(gU[2]);
        const float r = sigm((float)ar * swr + gir);    // b_hh_r folded upstream
        const float z = sigm((float)az * swz + giz);    // b_hh_z folded upstream
        const float n = ftanh(gin + r * ((float)an * swn + bhn));
        const float hnew = (1.0f - z) * n + z * hprev;
        hprev = hnew;
        // 4. publish h (i8, double-buffered) + state-sequence store (grp 0,1
        //    cover all 32 units of this wave; grps 2,3 are duplicates)
        if (grp < 2) {
            hb8[nxt * 256 + unit] = (char)(int)rintf(hnew * 127.0f);
            if (!DEC) hsp[0] = f2bf(hnew);
            else      ssp[0] = hnew;
        }
        if (!DEC) hsp += Hn; else ssp += Hn;
        // 5. barrier WITHOUT vmcnt drain (keep prefetch/stores in flight)
        asm volatile("s_waitcnt lgkmcnt(0)\n\ts_barrier" ::: "memory");
    };

    for (int t = 0; t < Ln; t += 2) {
        step(t, giA, giB);
        step(t + 1, giB, giA);
    }

    if (!DEC) {
        if (grp < 2) last_h[b * Hn + unit] = hprev;
    }
}

// ---------------------------------------------------------------------------
// K3a: attention scores h_proj[b,l] = h_seq[b,l,:]·wa_h on 512 blocks
// (8 L-chunks x 64 batches) — the old 64-block phase A was latency-bound on
// 25% of the CUs. Same dot order as before => bit-identical scores.
// ---------------------------------------------------------------------------
__global__ __launch_bounds__(256) void k3a_scores(const unsigned short* __restrict__ h_seq,
        const float* __restrict__ Wattn, float* __restrict__ h_proj) {
    const int bid = blockIdx.x;           // 0..511
    const int b = bid >> 3, chunk = bid & 7;
    const int tid = threadIdx.x, wv = tid >> 6, lane = tid & 63;
    __shared__ float wah[Hn];
    wah[tid] = Wattn[Hn + tid];           // wa_h = W_attn[0, H:2H]
    __syncthreads();

    const unsigned short* hb_ = h_seq + (long)b * Ln * Hn;
    const float4 wv4 = ((const float4*)wah)[lane];

    for (int it = 0; it < 8; ++it) {
        const int lbase = chunk * 128 + it * 16 + wv * 4;   // 4 waves x 4 rows
        const uint2 w0 = ((const uint2*)(hb_ + (long)(lbase + 0) * Hn))[lane];
        const uint2 w1 = ((const uint2*)(hb_ + (long)(lbase + 1) * Hn))[lane];
        const uint2 w2 = ((const uint2*)(hb_ + (long)(lbase + 2) * Hn))[lane];
        const uint2 w3 = ((const uint2*)(hb_ + (long)(lbase + 3) * Hn))[lane];
        float p0 = __uint_as_float(w0.x << 16) * wv4.x + __uint_as_float(w0.x & 0xffff0000u) * wv4.y
                 + __uint_as_float(w0.y << 16) * wv4.z + __uint_as_float(w0.y & 0xffff0000u) * wv4.w;
        float p1 = __uint_as_float(w1.x << 16) * wv4.x + __uint_as_float(w1.x & 0xffff0000u) * wv4.y
                 + __uint_as_float(w1.y << 16) * wv4.z + __uint_as_float(w1.y & 0xffff0000u) * wv4.w;
        float p2 = __uint_as_float(w2.x << 16) * wv4.x + __uint_as_float(w2.x & 0xffff0000u) * wv4.y
                 + __uint_as_float(w2.y << 16) * wv4.z + __uint_as_float(w2.y & 0xffff0000u) * wv4.w;
        float p3 = __uint_as_float(w3.x << 16) * wv4.x + __uint_as_float(w3.x & 0xffff0000u) * wv4.y
                 + __uint_as_float(w3.y << 16) * wv4.z + __uint_as_float(w3.y & 0xffff0000u) * wv4.w;
#pragma unroll
        for (int s = 1; s < 64; s <<= 1) {
            p0 += __shfl_xor(p0, s);
            p1 += __shfl_xor(p1, s);
            p2 += __shfl_xor(p2, s);
            p3 += __shfl_xor(p3, s);
        }
        if (lane == 0) {
            float* hp = h_proj + (long)b * Ln + lbase;
            hp[0] = p0; hp[1] = p1; hp[2] = p2; hp[3] = p3;
        }
    }
}

// ---------------------------------------------------------------------------
// K3b: alpha = softmax(h_proj[b,:]); c = sum_l alpha*h_seq; gi_d = c@Wihd^T + b
// ---------------------------------------------------------------------------
__global__ __launch_bounds__(256) void k3b_ctx(const float* __restrict__ h_proj,
        const unsigned short* __restrict__ h_seq, const float* __restrict__ Wihd,
        const float* __restrict__ bihd, const float* __restrict__ bhhd,
        float* __restrict__ gi_d) {
    const int b = blockIdx.x;
    const int tid = threadIdx.x;
    const int wv = tid >> 6, lane = tid & 63;
    __shared__ float alpha[Ln];
    __shared__ float red[8];
    __shared__ float cbuf[Hn];

    const unsigned short* hb_ = h_seq + (long)b * Ln * Hn;

    // softmax over h_proj[b,:]
    const float4 hp4 = ((const float4*)(h_proj + (long)b * Ln))[tid];
    float m = fmaxf(fmaxf(hp4.x, hp4.y), fmaxf(hp4.z, hp4.w));
#pragma unroll
    for (int s = 1; s < 64; s <<= 1) m = fmaxf(m, __shfl_xor(m, s));
    if (lane == 0) red[wv] = m;
    __syncthreads();
    m = fmaxf(fmaxf(red[0], red[1]), fmaxf(red[2], red[3]));
    const float e0 = __expf(hp4.x - m), e1 = __expf(hp4.y - m);
    const float e2 = __expf(hp4.z - m), e3 = __expf(hp4.w - m);
    float ss = e0 + e1 + e2 + e3;
#pragma unroll
    for (int s = 1; s < 64; s <<= 1) ss += __shfl_xor(ss, s);
    if (lane == 0) red[4 + wv] = ss;
    __syncthreads();
    const float inv = 1.0f / (red[4] + red[5] + red[6] + red[7]);
    ((float4*)alpha)[tid] = make_float4(e0 * inv, e1 * inv, e2 * inv, e3 * inv);
    __syncthreads();

    // context accumulation (column-coalesced)
    float accv = 0.0f;
    const unsigned short* hs = hb_ + tid;
    for (int l = 0; l < Ln; ++l) accv += alpha[l] * bf2f(hs[(long)l * Hn]);
    cbuf[tid] = accv;
    __syncthreads();

    // gi_d = c @ Wihd^T + biases
    for (int c = wv; c < THn; c += 4) {
        const float4 wr = ((const float4*)(Wihd + (long)c * Hn))[lane];
        const float4 cc = ((const float4*)cbuf)[lane];
        float p = wr.x * cc.x + wr.y * cc.y + wr.z * cc.z + wr.w * cc.w;
#pragma unroll
        for (int s = 1; s < 64; s <<= 1) p += __shfl_xor(p, s);
        if (lane == 0)
            gi_d[(long)b * THn + c] = p + bihd[c] + (c < 512 ? bhhd[c] : 0.0f);
    }
}

// ---------------------------------------------------------------------------
// K5a: y[b,l] = sigm(s_seq[b,l,:]·W_dec + b_dec) on 512 blocks (8 chunks x 64)
// ---------------------------------------------------------------------------
__global__ __launch_bounds__(256) void k5a_y(const float* __restrict__ s_seq,
        const float* __restrict__ Wdec, const float* __restrict__ bdec,
        float* __restrict__ y) {
    const int bid = blockIdx.x;           // 0..511
    const int b = bid >> 3, chunk = bid & 7;
    const int tid = threadIdx.x, wv = tid >> 6, lane = tid & 63;
    __shared__ float wd[Hn];
    wd[tid] = Wdec[tid];
    __syncthreads();

    const float* sb = s_seq + (long)b * Ln * Hn;
    const float4 wd4 = ((const float4*)wd)[lane];
    const float bd = bdec[0];

    for (int it = 0; it < 8; ++it) {
        const int lbase = chunk * 128 + it * 16 + wv * 4;
        const float4 v0 = ((const float4*)(sb + (long)(lbase + 0) * Hn))[lane];
        const float4 v1 = ((const float4*)(sb + (long)(lbase + 1) * Hn))[lane];
        const float4 v2 = ((const float4*)(sb + (long)(lbase + 2) * Hn))[lane];
        const float4 v3 = ((const float4*)(sb + (long)(lbase + 3) * Hn))[lane];
        float p0 = v0.x * wd4.x + v0.y * wd4.y + v0.z * wd4.z + v0.w * wd4.w;
        float p1 = v1.x * wd4.x + v1.y * wd4.y + v1.z * wd4.z + v1.w * wd4.w;
        float p2 = v2.x * wd4.x + v2.y * wd4.y + v2.z * wd4.z + v2.w * wd4.w;
        float p3 = v3.x * wd4.x + v3.y * wd4.y + v3.z * wd4.z + v3.w * wd4.w;
#pragma unroll
        for (int s = 1; s < 64; s <<= 1) {
            p0 += __shfl_xor(p0, s);
            p1 += __shfl_xor(p1, s);
            p2 += __shfl_xor(p2, s);
            p3 += __shfl_xor(p3, s);
        }
        if (lane == 0) {
            float* yp = y + (long)b * Ln + lbase;
            yp[0] = sigm(p0 + bd); yp[1] = sigm(p1 + bd);
            yp[2] = sigm(p2 + bd); yp[3] = sigm(p3 + bd);
        }
    }
}

// ---------------------------------------------------------------------------
// K5b: out[b,o] = y[b,:]·W_out[o,:] + b_out[o]
// ---------------------------------------------------------------------------
__global__ __launch_bounds__(256) void k5b_out(const float* __restrict__ y,
        const float* __restrict__ Wout, const float* __restrict__ bout,
        float* __restrict__ out) {
    const int b = blockIdx.x;
    const int tid = threadIdx.x, wv = tid >> 6, lane = tid & 63;
    __shared__ float yl[Ln];
    ((float4*)yl)[tid] = ((const float4*)(y + (long)b * Ln))[tid];
    __syncthreads();

    for (int o = wv; o < ONn; o += 4) {
        const float* wr = Wout + (long)o * Ln;
        float p = 0.0f;
#pragma unroll
        for (int i = 0; i < 16; ++i) p += yl[lane + 64 * i] * wr[lane + 64 * i];
#pragma unroll
        for (int s = 1; s < 64; s <<= 1) p += __shfl_xor(p, s);
        if (lane == 0) out[b * ONn + o] = p + bout[o];
    }
}

// ---------------------------------------------------------------------------
extern "C" void kernel_launch(void* const* d_in, const int* in_sizes, int n_in,
                              void* d_out, int out_size, void* d_ws, size_t ws_size,
                              hipStream_t stream) {
    const float* x      = (const float*)d_in[0];
    const float* Wih_e  = (const float*)d_in[1];
    const float* Whh_e  = (const float*)d_in[2];
    const float* bih_e  = (const float*)d_in[3];
    const float* bhh_e  = (const float*)d_in[4];
    const float* Wih_d  = (const float*)d_in[5];
    const float* Whh_d  = (const float*)d_in[6];
    const float* bih_d  = (const float*)d_in[7];
    const float* bhh_d  = (const float*)d_in[8];
    const float* Wdec   = (const float*)d_in[9];
    const float* bdec   = (const float*)d_in[10];
    const float* Wattn  = (const float*)d_in[11];
    const float* Wout   = (const float*)d_in[13];
    const float* bout   = (const float*)d_in[14];
    float* out = (float*)d_out;

    char* ws = (char*)d_ws;
    unsigned short* gi_e  = (unsigned short*)ws;                    // [0, 100663296) 96 MB
    unsigned short* h_seq = (unsigned short*)(ws + 100663296);      // 32 MB
    float* last_h = (float*)(ws + 134217728);                       // 64 KB
    float* gi_d   = (float*)(ws + 134283264);                       // 192 KB
    float* h_proj = (float*)(ws + 134479872);                       // 256 KB
    float* y      = (float*)(ws + 134742016);                       // 256 KB
    float* s_seq  = (float*)ws;                                     // reuse gi_e (dead after enc), 64 MB

    k1_gi<<<512, 256, 0, stream>>>(x, Wih_e, bih_e, bhh_e, gi_e);
    k_rec<0><<<Bn, 512, 0, stream>>>(Whh_e, bhh_e, gi_e, nullptr, nullptr,
                                     h_seq, nullptr, last_h);
    k3a_scores<<<512, 256, 0, stream>>>(h_seq, Wattn, h_proj);
    k3b_ctx<<<Bn, 256, 0, stream>>>(h_proj, h_seq, Wih_d, bih_d, bhh_d, gi_d);
    k_rec<1><<<Bn, 512, 0, stream>>>(Whh_d, bhh_d, nullptr, gi_d, last_h,
                                     nullptr, s_seq, nullptr);
    k5a_y<<<512, 256, 0, stream>>>(s_seq, Wdec, bdec, y);
    k5b_out<<<Bn, 256, 0, stream>>>(y, Wout, bout, out);
}